// Round 16
// baseline (874.603 us; speedup 1.0000x reference)
//
#include <hip/hip_runtime.h>
#include <cstdint>
#include <math.h>

#define DEV __device__ __forceinline__

static constexpr int BQ = 8, SEQN = 1000, CIN = 32, NH = 8;
static constexpr int NLAY = 4;
static constexpr int NTOT_C = 1365;
static constexpr int M_REAL = BQ * NTOT_C;   // 10920
static constexpr int M_PAD  = 11008;         // 86*128 = 344*32 = 2752*4

DEV float bf2f(unsigned short u){ return __uint_as_float(((unsigned)u) << 16); }
DEV unsigned short f2bf(float f){
  unsigned u = __float_as_uint(f);
  u += 0x7fffu + ((u >> 16) & 1u);
  return (unsigned short)(u >> 16);
}

typedef __bf16 bf16x8 __attribute__((ext_vector_type(8)));
typedef float  f32x4  __attribute__((ext_vector_type(4)));
typedef unsigned short u16x8 __attribute__((ext_vector_type(8)));

#define GLD_LDS16(gp, lp) __builtin_amdgcn_global_load_lds( \
    (const __attribute__((address_space(1))) void*)(gp), \
    (__attribute__((address_space(3))) void*)(lp), 16, 0, 0)

template<int N> DEV void waitcnt_vm(){
  asm volatile("s_waitcnt vmcnt(%0)" :: "i"(N) : "memory");
}
DEV void waitcnt_lgkm0(){ asm volatile("s_waitcnt lgkmcnt(0)" ::: "memory"); }
DEV void cfence(){ asm volatile("" ::: "memory"); }

DEV float gelu_f(float x){
  float z = 0.7978845608028654f * (x + 0.044715f * x * x * x);
  z = fminf(fmaxf(z, -10.f), 10.f);
  float e = __expf(2.f * z);
  float th = (e - 1.f) / (e + 1.f);
  return 0.5f * x * (1.f + th);
}

// ---------------- sinusoid PE table (fp32), SEQN x 512 ----------------
__global__ __launch_bounds__(256) void pe_kernel(float* __restrict__ pe)
{
  int idx = blockIdx.x * 256 + threadIdx.x;
  int d = idx & 511, s = idx >> 9;
  if (s >= SEQN) return;
  float e2 = (float)(d & ~1);
  float freq = exp2f(e2 * (-13.287712379549449f / 512.0f));
  float ang = (float)s * freq;
  pe[idx] = (d & 1) ? cosf(ang) : sinf(ang);
}

// ---------------- conv1d (k=3 circular), tiled: 64 s x 128 d per block ----------------
__global__ __launch_bounds__(256) void conv_kernel(const float* __restrict__ x,
    const float* __restrict__ w, const float* __restrict__ pe, float* __restrict__ seqf)
{
  __shared__ float ws_w[128 * 97];
  __shared__ __align__(16) float xs[66][32];
  int b = blockIdx.z, s0 = blockIdx.y * 64, d0 = blockIdx.x * 128;
  int tid = threadIdx.x;
  for (int i = tid; i < 128 * 96; i += 256){
    int r = i / 96, c = i - r * 96;
    ws_w[r * 97 + c] = w[(size_t)(d0 + r) * 96 + c];
  }
  for (int i = tid; i < 66 * 32; i += 256){
    int r = i >> 5, c = i & 31;
    int ss = s0 + r - 1;
    ss = (ss < 0) ? (ss + SEQN) : (ss >= SEQN ? ss - SEQN : ss);
    xs[r][c] = x[((size_t)b * SEQN + ss) * CIN + c];
  }
  __syncthreads();
  int dl = tid & 127, sh = tid >> 7;
  float wr[96];
  #pragma unroll
  for (int i = 0; i < 96; i++) wr[i] = ws_w[dl * 97 + i];
  int d = d0 + dl;
  for (int si = 0; si < 32; si++){
    int sl = sh * 32 + si;
    int s = s0 + sl;
    float acc = 0.f;
    #pragma unroll
    for (int kk = 0; kk < 3; kk++){
      const float* xr = xs[sl + kk];
      #pragma unroll
      for (int c = 0; c < 32; c++) acc += xr[c] * wr[c * 3 + kk];
    }
    float outv = (s < SEQN) ? acc + pe[(size_t)s * 512 + d] : 0.f;
    seqf[((size_t)b * NTOT_C + s) * 512 + d] = outv;
  }
}

// ---------------- max-pool one pyramid level ----------------
__global__ __launch_bounds__(256) void pool_kernel(float* __restrict__ seqf,
    int inOff, int outOff, int outSz)
{
  int e = blockIdx.x * 256 + threadIdx.x;
  int d = e & 511;
  int r = e >> 9;
  int i = r % outSz;
  int b = r / outSz;
  const float* src = seqf + ((size_t)b * NTOT_C + inOff + 4 * i) * 512 + d;
  float m = fmaxf(fmaxf(src[0], src[512]), fmaxf(src[1024], src[1536]));
  seqf[((size_t)b * NTOT_C + outOff + i) * 512 + d] = m;
}

// ---------------- initial LayerNorm (fp32 in), wave-per-row, bf16 out only ----------------
__global__ __launch_bounds__(256) void ln4_kernel(const float* __restrict__ xin,
    unsigned short* __restrict__ outb,
    const float* __restrict__ sg, const float* __restrict__ bg, int M)
{
  int row = blockIdx.x * 4 + (threadIdx.x >> 6);
  int lane = threadIdx.x & 63;
  size_t base = (size_t)row * 512 + lane * 8;
  if (row >= M){
    u16x8 z8 = {0, 0, 0, 0, 0, 0, 0, 0};
    *reinterpret_cast<u16x8*>(outb + base) = z8;
    return;
  }
  f32x4 v0 = *reinterpret_cast<const f32x4*>(xin + base);
  f32x4 v1 = *reinterpret_cast<const f32x4*>(xin + base + 4);
  float sall = v0[0] + v0[1] + v0[2] + v0[3] + v1[0] + v1[1] + v1[2] + v1[3];
  #pragma unroll
  for (int o = 32; o; o >>= 1) sall += __shfl_xor(sall, o, 64);
  float mean = sall * (1.f / 512.f);
  float d[8];
  #pragma unroll
  for (int e = 0; e < 4; e++){ d[e] = v0[e] - mean; d[4 + e] = v1[e] - mean; }
  float sq = 0.f;
  #pragma unroll
  for (int e = 0; e < 8; e++) sq += d[e] * d[e];
  #pragma unroll
  for (int o = 32; o; o >>= 1) sq += __shfl_xor(sq, o, 64);
  float rstd = 1.f / sqrtf(sq * (1.f / 512.f) + 1e-5f);
  f32x4 s0 = *reinterpret_cast<const f32x4*>(sg + lane * 8);
  f32x4 s1 = *reinterpret_cast<const f32x4*>(sg + lane * 8 + 4);
  f32x4 g0 = *reinterpret_cast<const f32x4*>(bg + lane * 8);
  f32x4 g1 = *reinterpret_cast<const f32x4*>(bg + lane * 8 + 4);
  u16x8 yb;
  #pragma unroll
  for (int e = 0; e < 4; e++){
    yb[e]     = f2bf(d[e] * rstd * s0[e] + g0[e]);
    yb[4 + e] = f2bf(d[4 + e] * rstd * s1[e] + g1[e]);
  }
  *reinterpret_cast<u16x8*>(outb + base) = yb;
}

// ---------------- fused residual-add + LayerNorm (bf16 in) ----------------
// MODE 0: write seqb (bf16). MODE 1 (final): write mapped rows of `out` (fp32).
template<int MODE>
__global__ __launch_bounds__(256) void lnres4_kernel(const unsigned short* __restrict__ cin,
    unsigned short* __restrict__ seqb, float* __restrict__ out,
    const float* __restrict__ sg, const float* __restrict__ bg, int M)
{
  int row = blockIdx.x * 4 + (threadIdx.x >> 6);
  int lane = threadIdx.x & 63;
  size_t base = (size_t)row * 512 + lane * 8;
  if (row >= M){
    if (MODE == 0){
      u16x8 z8 = {0, 0, 0, 0, 0, 0, 0, 0};
      *reinterpret_cast<u16x8*>(seqb + base) = z8;
    }
    return;
  }
  u16x8 cv = *reinterpret_cast<const u16x8*>(cin + base);
  u16x8 rv = *reinterpret_cast<const u16x8*>(seqb + base);
  float v[8];
  #pragma unroll
  for (int e = 0; e < 8; e++) v[e] = bf2f(cv[e]) + bf2f(rv[e]);
  float sall = 0.f;
  #pragma unroll
  for (int e = 0; e < 8; e++) sall += v[e];
  #pragma unroll
  for (int o = 32; o; o >>= 1) sall += __shfl_xor(sall, o, 64);
  float mean = sall * (1.f / 512.f);
  float sq = 0.f;
  #pragma unroll
  for (int e = 0; e < 8; e++){ v[e] -= mean; sq += v[e] * v[e]; }
  #pragma unroll
  for (int o = 32; o; o >>= 1) sq += __shfl_xor(sq, o, 64);
  float rstd = 1.f / sqrtf(sq * (1.f / 512.f) + 1e-5f);
  f32x4 s0 = *reinterpret_cast<const f32x4*>(sg + lane * 8);
  f32x4 s1 = *reinterpret_cast<const f32x4*>(sg + lane * 8 + 4);
  f32x4 g0 = *reinterpret_cast<const f32x4*>(bg + lane * 8);
  f32x4 g1 = *reinterpret_cast<const f32x4*>(bg + lane * 8 + 4);
  f32x4 y0, y1;
  #pragma unroll
  for (int e = 0; e < 4; e++){
    y0[e] = v[e] * rstd * s0[e] + g0[e];
    y1[e] = v[4 + e] * rstd * s1[e] + g1[e];
  }
  if (MODE == 0){
    u16x8 yb;
    #pragma unroll
    for (int e = 0; e < 4; e++){ yb[e] = f2bf(y0[e]); yb[4 + e] = f2bf(y1[e]); }
    *reinterpret_cast<u16x8*>(seqb + base) = yb;
  } else {
    int b = row / NTOT_C, n = row - b * NTOT_C;
    int o;
    if      (n < 1000) o = n;
    else if (n < 1024) o = -1;
    else if (n < 1274) o = n - 24;
    else if (n < 1280) o = -1;
    else if (n < 1343) o = n - 30;
    else if (n == 1343) o = -1;
    else               o = n - 31;
    if (o >= 0){
      size_t ob = ((size_t)b * 1334 + o) * 512 + lane * 8;
      *reinterpret_cast<f32x4*>(out + ob) = y0;
      *reinterpret_cast<f32x4*>(out + ob + 4) = y1;
    }
  }
}

// ---------------- ALL weight transposes fp32(K,N) -> bf16(N,K), one dispatch ----------------
__global__ __launch_bounds__(256) void wconv_all(
    const float* __restrict__ wq, const float* __restrict__ wk,
    const float* __restrict__ wv, const float* __restrict__ wo,
    const float* __restrict__ w1, const float* __restrict__ w2,
    unsigned short* __restrict__ qkvT, unsigned short* __restrict__ woT,
    unsigned short* __restrict__ w1T, unsigned short* __restrict__ w2T)
{
  __shared__ float tile[32][33];
  int bid = blockIdx.x;
  const float* wl; unsigned short* wtl; int N, K, n0, k0;
  if (bid < 4096){
    int part = bid >> 10, t = bid & 1023;
    int l = t >> 8, t2 = t & 255;
    k0 = (t2 >> 4) * 32; n0 = (t2 & 15) * 32;
    N = 512; K = 512;
    const float* s = (part == 0) ? wq : (part == 1) ? wk : (part == 2) ? wv : wo;
    wl = s + (size_t)l * 512 * 512;
    wtl = (part < 3) ? (qkvT + (size_t)l * 1536 * 512 + (size_t)part * 512 * 512)
                     : (woT + (size_t)l * 512 * 512);
  } else if (bid < 8192){
    int t = bid - 4096, l = t >> 10, t2 = t & 1023;
    k0 = (t2 >> 6) * 32; n0 = (t2 & 63) * 32;
    N = 2048; K = 512;
    wl = w1 + (size_t)l * 512 * 2048;
    wtl = w1T + (size_t)l * 2048 * 512;
  } else {
    int t = bid - 8192, l = t >> 10, t2 = t & 1023;
    k0 = (t2 >> 4) * 32; n0 = (t2 & 15) * 32;
    N = 512; K = 2048;
    wl = w2 + (size_t)l * 2048 * 512;
    wtl = w2T + (size_t)l * 512 * 2048;
  }
  int c = threadIdx.x & 31, r8 = threadIdx.x >> 5;
  #pragma unroll
  for (int p = 0; p < 4; p++){ int r = r8 + p * 8; tile[r][c] = wl[(size_t)(k0 + r) * N + n0 + c]; }
  __syncthreads();
  #pragma unroll
  for (int p = 0; p < 4; p++){ int r = r8 + p * 8; wtl[(size_t)(n0 + r) * K + k0 + c] = f2bf(tile[c][r]); }
}

// ================= 4-wave bf16 MFMA GEMM, BK=64, XCD-co-located (r15 champion) =================
// EPI: 1 = bf16, 2 = bias+gelu -> bf16, 4 = bias -> bf16
template<int EPI, int BM, int BN>
__global__ __launch_bounds__(256) void gemm2_kernel(
    const unsigned short* __restrict__ A, const unsigned short* __restrict__ Wt,
    unsigned short* __restrict__ Cb, const float* __restrict__ bias,
    int N, int K, int GX, int GY)
{
  constexpr int MF = BM / 32, NF = BN / 32;
  constexpr int LA = BM / 32, LB = BN / 32;
  __shared__ __align__(16) unsigned short Abuf[2][BM * 64];
  __shared__ __align__(16) unsigned short Bbuf[2][BN * 64];
  const int tid = threadIdx.x;
  const int wid = tid >> 6, lane = tid & 63;
  const int wm2 = wid >> 1, wn2 = wid & 1;
  const int r16 = lane & 15, g = lane >> 4;

  int wg = blockIdx.x;
  int group = wg / (8 * GX);
  int rem   = wg - group * 8 * GX;
  int gbase = group * 8;
  int m_t, n_t;
  if (gbase + 8 <= GY){ m_t = gbase + (rem & 7); n_t = rem >> 3; }
  else { int r = GY - gbase; m_t = gbase + rem % r; n_t = rem / r; }
  const int m0 = m_t * BM, n0 = n_t * BN;

  const int row0 = tid >> 3;
  const int scol = ((tid & 7) ^ (row0 & 7)) * 8;
  const unsigned short* gAs = A  + (size_t)(m0 + row0) * K + scol;
  const unsigned short* gBs = Wt + (size_t)(n0 + row0) * K + scol;

  const int swz0 = ((0 + g) ^ (r16 & 7)) * 8;
  const int swz1 = ((4 + g) ^ (r16 & 7)) * 8;
  const int arow = (wm2 * (BM / 2) + r16) * 64;
  const int brow = (wn2 * (BN / 2) + r16) * 64;

  const int nt = K >> 6;
  f32x4 acc[MF][NF] = {};

  auto STAGE_A = [&](int buf, int kt){
    #pragma unroll
    for (int q = 0; q < LA; q++)
      GLD_LDS16(gAs + kt * 64 + (size_t)q * 32 * K, &Abuf[buf][q * 2048 + tid * 8]);
  };
  auto STAGE_B = [&](int buf, int kt){
    #pragma unroll
    for (int q = 0; q < LB; q++)
      GLD_LDS16(gBs + kt * 64 + (size_t)q * 32 * K, &Bbuf[buf][q * 2048 + tid * 8]);
  };

  cfence();
  STAGE_A(0, 0); STAGE_B(0, 0);
  if (nt > 1){ STAGE_A(1, 1); waitcnt_vm<LA>(); }
  else        { waitcnt_vm<0>(); }
  __builtin_amdgcn_s_barrier();
  cfence();

  for (int t = 0; t < nt; t++){
    const int d = t & 1;
    const unsigned short* Ab = Abuf[d];
    const unsigned short* Bb = Bbuf[d];

    bf16x8 a0[MF], b0[NF];
    #pragma unroll
    for (int m = 0; m < MF; m++) a0[m] = *reinterpret_cast<const bf16x8*>(&Ab[arow + m * 1024 + swz0]);
    #pragma unroll
    for (int n = 0; n < NF; n++) b0[n] = *reinterpret_cast<const bf16x8*>(&Bb[brow + n * 1024 + swz0]);
    if (t + 1 < nt){ cfence(); STAGE_B(d ^ 1, t + 1); cfence(); }
    __builtin_amdgcn_s_setprio(1);
    #pragma unroll
    for (int m = 0; m < MF; m++)
      #pragma unroll
      for (int n = 0; n < NF; n++)
        acc[m][n] = __builtin_amdgcn_mfma_f32_16x16x32_bf16(a0[m], b0[n], acc[m][n], 0, 0, 0);
    __builtin_amdgcn_s_setprio(0);

    bf16x8 a1[MF], b1v[NF];
    #pragma unroll
    for (int m = 0; m < MF; m++) a1[m] = *reinterpret_cast<const bf16x8*>(&Ab[arow + m * 1024 + swz1]);
    #pragma unroll
    for (int n = 0; n < NF; n++) b1v[n] = *reinterpret_cast<const bf16x8*>(&Bb[brow + n * 1024 + swz1]);
    waitcnt_lgkm0();
    __builtin_amdgcn_s_barrier();
    cfence();
    if (t + 2 < nt){ STAGE_A(d, t + 2); cfence(); }
    __builtin_amdgcn_s_setprio(1);
    #pragma unroll
    for (int m = 0; m < MF; m++)
      #pragma unroll
      for (int n = 0; n < NF; n++)
        acc[m][n] = __builtin_amdgcn_mfma_f32_16x16x32_bf16(a1[m], b1v[n], acc[m][n], 0, 0, 0);
    __builtin_amdgcn_s_setprio(0);

    if (t + 1 < nt){
      if (t + 2 < nt) waitcnt_vm<LA>();
      else            waitcnt_vm<0>();
      __builtin_amdgcn_s_barrier();
      cfence();
    }
  }

  const int colBase = n0 + wn2 * (BN / 2) + r16;
  #pragma unroll
  for (int m = 0; m < MF; m++){
    int row = m0 + wm2 * (BM / 2) + m * 16 + g * 4;
    #pragma unroll
    for (int n = 0; n < NF; n++){
      int col = colBase + n * 16;
      float bsv = (EPI >= 2) ? bias[col] : 0.f;
      #pragma unroll
      for (int j = 0; j < 4; j++){
        float v = acc[m][n][j];
        if (EPI >= 2) v += bsv;
        if (EPI == 2) v = gelu_f(v);
        Cb[(size_t)(row + j) * N + col] = f2bf(v);
      }
    }
  }
}

// ================= fused sparse-attention + WO GEMM =================
// delta[m0..m0+31] = attn(qkv rows) @ woT.  BM=32, BN=128, K=N=512, 4 waves.
// Phase 1: B(0),B(1) staged early; each wave computes attn for 8 rows into
// LDS ctx [32][512] bf16 with chunk-XOR swizzle (writer lane^(l&7), reader
// (t*8+kk*4+g)^(row&7) — same involution as gemm2, verified mapping).
// Phase 2: r15 K-loop with A resident in LDS (B-only 2-deep counted pipeline).
__global__ __launch_bounds__(256) void attnwo_kernel(
    const unsigned short* __restrict__ qkv, const unsigned short* __restrict__ Wt,
    unsigned short* __restrict__ Cb, int GX, int GY)
{
  __shared__ __align__(16) unsigned short ctxL[32 * 512];     // 32 KB
  __shared__ __align__(16) unsigned short Bbuf[2][128 * 64];  // 32 KB
  const int tid = threadIdx.x;
  const int wid = tid >> 6, lane = tid & 63;
  const int wm2 = wid >> 1, wn2 = wid & 1;
  const int r16 = lane & 15, g = lane >> 4;

  // XCD co-location (groups of 8 M-stripes)
  int wg = blockIdx.x;
  int group = wg / (8 * GX);
  int rem   = wg - group * 8 * GX;
  int gbase = group * 8;
  int m_t, n_t;
  if (gbase + 8 <= GY){ m_t = gbase + (rem & 7); n_t = rem >> 3; }
  else { int r = GY - gbase; m_t = gbase + rem % r; n_t = rem / r; }
  const int m0 = m_t * 32, n0 = n_t * 128;

  // stage B(0), B(1) early — latency hides under the attn phase
  const int row0 = tid >> 3;
  const int scol = ((tid & 7) ^ (row0 & 7)) * 8;
  const unsigned short* gBs = Wt + (size_t)(n0 + row0) * 512 + scol;
  cfence();
  #pragma unroll
  for (int q = 0; q < 4; q++) GLD_LDS16(gBs +      (size_t)q * 32 * 512, &Bbuf[0][q * 2048 + tid * 8]);
  #pragma unroll
  for (int q = 0; q < 4; q++) GLD_LDS16(gBs + 64 + (size_t)q * 32 * 512, &Bbuf[1][q * 2048 + tid * 8]);
  cfence();

  // ---- attn: wave wid handles local rows l = wid*8 .. wid*8+7 ----
  for (int i = 0; i < 8; i++){
    int l = wid * 8 + i;
    int grow = m0 + l;
    u16x8 ov = {0, 0, 0, 0, 0, 0, 0, 0};
    if (grow < M_REAL){
      int b = grow / NTOT_C, n = grow - b * NTOT_C;
      int ii, sz, of, cb, par;
      if (n < 1024){ ii = n;        sz = 1024; of = 0;    cb = -1;             par = 1024 + (ii >> 2); }
      else if (n < 1280){ ii = n - 1024; sz = 256; of = 1024; cb = 0    + 4 * ii; par = 1280 + (ii >> 2); }
      else if (n < 1344){ ii = n - 1280; sz = 64;  of = 1280; cb = 1024 + 4 * ii; par = 1344 + (ii >> 2); }
      else if (n < 1360){ ii = n - 1344; sz = 16;  of = 1344; cb = 1280 + 4 * ii; par = 1360 + (ii >> 2); }
      else if (n < 1364){ ii = n - 1360; sz = 4;   of = 1360; cb = 1344 + 4 * ii; par = 1364; }
      else { ii = 0; sz = 1; of = 1364; cb = 1360; par = -1; }

      int nb[10];
      #pragma unroll
      for (int s5 = 0; s5 < 5; s5++){ int pos = ii - 2 + s5; nb[s5] = (pos >= 0 && pos < sz) ? of + pos : -1; }
      #pragma unroll
      for (int r = 0; r < 4; r++) nb[5 + r] = (cb >= 0) ? cb + r : -1;
      nb[9] = par;

      const unsigned short* rows = qkv + ((size_t)b * NTOT_C) * 1536;
      u16x8 qv = *reinterpret_cast<const u16x8*>(rows + (size_t)n * 1536 + lane * 8);
      float qf[8];
      #pragma unroll
      for (int e = 0; e < 8; e++) qf[e] = bf2f(qv[e]);

      float sc[10];
      #pragma unroll
      for (int j = 0; j < 10; j++){
        int id = nb[j] >= 0 ? nb[j] : n;
        u16x8 kv = *reinterpret_cast<const u16x8*>(rows + (size_t)id * 1536 + 512 + lane * 8);
        float p = 0.f;
        #pragma unroll
        for (int e = 0; e < 8; e++) p += qf[e] * bf2f(kv[e]);
        p += __shfl_xor(p, 1, 64);
        p += __shfl_xor(p, 2, 64);
        p += __shfl_xor(p, 4, 64);
        sc[j] = (nb[j] >= 0) ? p * 0.125f : -1e30f;
      }
      float mx = sc[0];
      #pragma unroll
      for (int j = 1; j < 10; j++) mx = fmaxf(mx, sc[j]);
      float den = 0.f, wj[10];
      #pragma unroll
      for (int j = 0; j < 10; j++){
        wj[j] = (nb[j] >= 0) ? expf(sc[j] - mx) : 0.f;
        den += wj[j];
      }
      float rden = 1.f / den;
      float accv[8] = {};
      #pragma unroll
      for (int j = 0; j < 10; j++){
        int id = nb[j] >= 0 ? nb[j] : n;
        u16x8 vv = *reinterpret_cast<const u16x8*>(rows + (size_t)id * 1536 + 1024 + lane * 8);
        float w = wj[j];
        #pragma unroll
        for (int e = 0; e < 8; e++) accv[e] += w * bf2f(vv[e]);
      }
      #pragma unroll
      for (int e = 0; e < 8; e++) ov[e] = f2bf(accv[e] * rden);
    }
    // chunk-swizzled LDS write: chunk lane -> slot lane^(l&7)
    *reinterpret_cast<u16x8*>(&ctxL[l * 512 + ((lane ^ (l & 7)) * 8)]) = ov;
  }
  __syncthreads();      // ctx writes + staged B drained (full-drain semantics)
  cfence();

  // ---- K-loop: A resident in ctxL, B 2-deep counted pipeline (nt=8) ----
  const int arowL = wm2 * 16 + r16;          // local A row for this lane
  const int ax = arowL & 7;
  const int brow = (wn2 * 64 + r16) * 64;
  const int swz0 = ((0 + g) ^ (r16 & 7)) * 8;
  const int swz1 = ((4 + g) ^ (r16 & 7)) * 8;
  f32x4 acc[4] = {};

  for (int t = 0; t < 8; t++){
    const int d = t & 1;
    const unsigned short* Bb = Bbuf[d];
    int c0 = t * 8 + g, c1 = t * 8 + 4 + g;  // chunk indices for kk=0/1
    bf16x8 a0 = *reinterpret_cast<const bf16x8*>(&ctxL[arowL * 512 + ((c0 ^ ax) * 8)]);
    bf16x8 b0[4];
    #pragma unroll
    for (int n = 0; n < 4; n++) b0[n] = *reinterpret_cast<const bf16x8*>(&Bb[brow + n * 1024 + swz0]);
    __builtin_amdgcn_s_setprio(1);
    #pragma unroll
    for (int n = 0; n < 4; n++)
      acc[n] = __builtin_amdgcn_mfma_f32_16x16x32_bf16(a0, b0[n], acc[n], 0, 0, 0);
    __builtin_amdgcn_s_setprio(0);

    bf16x8 a1 = *reinterpret_cast<const bf16x8*>(&ctxL[arowL * 512 + ((c1 ^ ax) * 8)]);
    bf16x8 b1v[4];
    #pragma unroll
    for (int n = 0; n < 4; n++) b1v[n] = *reinterpret_cast<const bf16x8*>(&Bb[brow + n * 1024 + swz1]);
    waitcnt_lgkm0();
    __builtin_amdgcn_s_barrier();            // Bbuf[d] reads closed block-wide
    cfence();
    if (t + 2 < 8){
      #pragma unroll
      for (int q = 0; q < 4; q++)
        GLD_LDS16(gBs + (t + 2) * 64 + (size_t)q * 32 * 512, &Bbuf[d][q * 2048 + tid * 8]);
      cfence();
    }
    __builtin_amdgcn_s_setprio(1);
    #pragma unroll
    for (int n = 0; n < 4; n++)
      acc[n] = __builtin_amdgcn_mfma_f32_16x16x32_bf16(a1, b1v[n], acc[n], 0, 0, 0);
    __builtin_amdgcn_s_setprio(0);

    if (t + 1 < 8){
      if (t + 2 < 8) waitcnt_vm<4>();        // stage(t+1) done; stage(t+2) in flight
      else           waitcnt_vm<0>();
      __builtin_amdgcn_s_barrier();
      cfence();
    }
  }

  // ---- epilogue: delta bf16 (no bias) ----
  const int colBase = n0 + wn2 * 64 + r16;
  int row = m0 + wm2 * 16 + g * 4;
  #pragma unroll
  for (int n = 0; n < 4; n++){
    int col = colBase + n * 16;
    #pragma unroll
    for (int j = 0; j < 4; j++)
      Cb[(size_t)(row + j) * 512 + col] = f2bf(acc[n][j]);
  }
}

extern "C" void kernel_launch(void* const* d_in, const int* in_sizes, int n_in,
                              void* d_out, int out_size, void* d_ws, size_t ws_size,
                              hipStream_t stream)
{
  const float* x      = (const float*)d_in[0];
  const float* conv_w = (const float*)d_in[1];
  const float* norm_s = (const float*)d_in[2];
  const float* norm_b = (const float*)d_in[3];
  const float* wq     = (const float*)d_in[4];
  const float* wk     = (const float*)d_in[5];
  const float* wv     = (const float*)d_in[6];
  const float* wo     = (const float*)d_in[7];
  const float* ln1_s  = (const float*)d_in[8];
  const float* ln1_b  = (const float*)d_in[9];
  const float* w1     = (const float*)d_in[10];
  const float* b1     = (const float*)d_in[11];
  const float* w2     = (const float*)d_in[12];
  const float* b2     = (const float*)d_in[13];
  const float* ln2_s  = (const float*)d_in[14];
  const float* ln2_b  = (const float*)d_in[15];
  float* out = (float*)d_out;

  char* ws = (char*)d_ws;
  size_t off = 0;
  auto alloc = [&](size_t bytes) -> char* {
    char* p = ws + off; off += (bytes + 255) & ~(size_t)255; return p;
  };
  unsigned short* qkvT = (unsigned short*)alloc((size_t)NLAY * 1536 * 512 * 2);
  unsigned short* woT  = (unsigned short*)alloc((size_t)NLAY * 512 * 512 * 2);
  unsigned short* w1T  = (unsigned short*)alloc((size_t)NLAY * 2048 * 512 * 2);
  unsigned short* w2T  = (unsigned short*)alloc((size_t)NLAY * 512 * 2048 * 2);
  float*          seqf = (float*)alloc((size_t)M_PAD * 512 * 4);
  unsigned short* seqb = (unsigned short*)alloc((size_t)M_PAD * 512 * 2);
  float*          buff = (float*)alloc((size_t)M_PAD * 512 * 4);   // pe (pre-loop) + delta (in-loop)
  unsigned short* qkvb = (unsigned short*)alloc((size_t)M_PAD * 1536 * 2);
  unsigned short* ffn1 = qkvb;                 // alias: M_PAD x 2048 fits in qkvb region
  float*          pe   = buff;                 // alias, pre-loop only
  unsigned short* delta = (unsigned short*)buff;  // alias, in-loop bf16 GEMM output

  wconv_all<<<12288, 256, 0, stream>>>(wq, wk, wv, wo, w1, w2, qkvT, woT, w1T, w2T);

  pe_kernel<<<(SEQN * 512) / 256, 256, 0, stream>>>(pe);
  conv_kernel<<<dim3(4,16,BQ), 256, 0, stream>>>(x, conv_w, pe, seqf);
  const int psz[6]  = {1024, 256, 64, 16, 4, 1};
  const int poff[6] = {0, 1024, 1280, 1344, 1360, 1364};
  for (int l = 0; l < 5; l++)
    pool_kernel<<<(BQ * psz[l+1] * 512) / 256, 256, 0, stream>>>(seqf, poff[l], poff[l+1], psz[l+1]);
  ln4_kernel<<<M_PAD / 4, 256, 0, stream>>>(seqf, seqb, norm_s, norm_b, M_REAL);

  for (int l = 0; l < NLAY; l++){
    // QKV: 128x128, GX=12 x GY=86, XCD-co-located
    gemm2_kernel<1,128,128><<<12*86,256,0,stream>>>(seqb, qkvT + (size_t)l*1536*512, qkvb, nullptr, 1536, 512, 12, 86);
    // fused attn + WO: 32x128 tiles, GX=4 x GY=344 -> bf16 delta
    attnwo_kernel<<<4*344,256,0,stream>>>(qkvb, woT + (size_t)l*512*512, delta, 4, 344);
    lnres4_kernel<0><<<M_PAD / 4,256,0,stream>>>(delta, seqb, nullptr, ln1_s + l*512, ln1_b + l*512, M_REAL);
    // FFN1: 128x128, GX=16 x GY=86; bias+gelu -> bf16
    gemm2_kernel<2,128,128><<<16*86,256,0,stream>>>(seqb, w1T + (size_t)l*2048*512, ffn1, b1 + l*2048, 2048, 512, 16, 86);
    // FFN2: 64x128, GX=4 x GY=172, K=2048; bias -> bf16 delta
    gemm2_kernel<4,64,128><<<4*172,256,0,stream>>>(ffn1, w2T + (size_t)l*512*2048, delta, b2 + l*512, 512, 2048, 4, 172);
    if (l < NLAY - 1)
      lnres4_kernel<0><<<M_PAD / 4,256,0,stream>>>(delta, seqb, nullptr, ln2_s + l*512, ln2_b + l*512, M_REAL);
    else
      lnres4_kernel<1><<<M_PAD / 4,256,0,stream>>>(delta, seqb, out, ln2_s + l*512, ln2_b + l*512, M_REAL);
  }
}

// Round 17
// 676.922 us; speedup vs baseline: 1.2920x; 1.2920x over previous
//
#include <hip/hip_runtime.h>
#include <cstdint>
#include <math.h>

#define DEV __device__ __forceinline__

static constexpr int BQ = 8, SEQN = 1000, CIN = 32, NH = 8;
static constexpr int NLAY = 4;
static constexpr int NTOT_C = 1365;
static constexpr int M_REAL = BQ * NTOT_C;   // 10920
static constexpr int M_PAD  = 11008;         // 86*128 = 172*64 = 2752*4

DEV float bf2f(unsigned short u){ return __uint_as_float(((unsigned)u) << 16); }
DEV unsigned short f2bf(float f){
  unsigned u = __float_as_uint(f);
  u += 0x7fffu + ((u >> 16) & 1u);
  return (unsigned short)(u >> 16);
}

typedef __bf16 bf16x8 __attribute__((ext_vector_type(8)));
typedef float  f32x4  __attribute__((ext_vector_type(4)));
typedef unsigned short u16x8 __attribute__((ext_vector_type(8)));

#define GLD_LDS16(gp, lp) __builtin_amdgcn_global_load_lds( \
    (const __attribute__((address_space(1))) void*)(gp), \
    (__attribute__((address_space(3))) void*)(lp), 16, 0, 0)

template<int N> DEV void waitcnt_vm(){
  asm volatile("s_waitcnt vmcnt(%0)" :: "i"(N) : "memory");
}
DEV void waitcnt_lgkm0(){ asm volatile("s_waitcnt lgkmcnt(0)" ::: "memory"); }
DEV void cfence(){ asm volatile("" ::: "memory"); }

DEV float gelu_f(float x){
  float z = 0.7978845608028654f * (x + 0.044715f * x * x * x);
  z = fminf(fmaxf(z, -10.f), 10.f);
  float e = __expf(2.f * z);
  float th = (e - 1.f) / (e + 1.f);
  return 0.5f * x * (1.f + th);
}

// ---------------- sinusoid PE table (fp32), SEQN x 512 ----------------
__global__ __launch_bounds__(256) void pe_kernel(float* __restrict__ pe)
{
  int idx = blockIdx.x * 256 + threadIdx.x;
  int d = idx & 511, s = idx >> 9;
  if (s >= SEQN) return;
  float e2 = (float)(d & ~1);
  float freq = exp2f(e2 * (-13.287712379549449f / 512.0f));
  float ang = (float)s * freq;
  pe[idx] = (d & 1) ? cosf(ang) : sinf(ang);
}

// ---------------- conv1d (k=3 circular), tiled: 64 s x 128 d per block ----------------
__global__ __launch_bounds__(256) void conv_kernel(const float* __restrict__ x,
    const float* __restrict__ w, const float* __restrict__ pe, float* __restrict__ seqf)
{
  __shared__ float ws_w[128 * 97];
  __shared__ __align__(16) float xs[66][32];
  int b = blockIdx.z, s0 = blockIdx.y * 64, d0 = blockIdx.x * 128;
  int tid = threadIdx.x;
  for (int i = tid; i < 128 * 96; i += 256){
    int r = i / 96, c = i - r * 96;
    ws_w[r * 97 + c] = w[(size_t)(d0 + r) * 96 + c];
  }
  for (int i = tid; i < 66 * 32; i += 256){
    int r = i >> 5, c = i & 31;
    int ss = s0 + r - 1;
    ss = (ss < 0) ? (ss + SEQN) : (ss >= SEQN ? ss - SEQN : ss);
    xs[r][c] = x[((size_t)b * SEQN + ss) * CIN + c];
  }
  __syncthreads();
  int dl = tid & 127, sh = tid >> 7;
  float wr[96];
  #pragma unroll
  for (int i = 0; i < 96; i++) wr[i] = ws_w[dl * 97 + i];
  int d = d0 + dl;
  for (int si = 0; si < 32; si++){
    int sl = sh * 32 + si;
    int s = s0 + sl;
    float acc = 0.f;
    #pragma unroll
    for (int kk = 0; kk < 3; kk++){
      const float* xr = xs[sl + kk];
      #pragma unroll
      for (int c = 0; c < 32; c++) acc += xr[c] * wr[c * 3 + kk];
    }
    float outv = (s < SEQN) ? acc + pe[(size_t)s * 512 + d] : 0.f;
    seqf[((size_t)b * NTOT_C + s) * 512 + d] = outv;
  }
}

// ---------------- max-pool one pyramid level ----------------
__global__ __launch_bounds__(256) void pool_kernel(float* __restrict__ seqf,
    int inOff, int outOff, int outSz)
{
  int e = blockIdx.x * 256 + threadIdx.x;
  int d = e & 511;
  int r = e >> 9;
  int i = r % outSz;
  int b = r / outSz;
  const float* src = seqf + ((size_t)b * NTOT_C + inOff + 4 * i) * 512 + d;
  float m = fmaxf(fmaxf(src[0], src[512]), fmaxf(src[1024], src[1536]));
  seqf[((size_t)b * NTOT_C + outOff + i) * 512 + d] = m;
}

// ---------------- initial LayerNorm (fp32 in), wave-per-row, bf16 out only ----------------
__global__ __launch_bounds__(256) void ln4_kernel(const float* __restrict__ xin,
    unsigned short* __restrict__ outb,
    const float* __restrict__ sg, const float* __restrict__ bg, int M)
{
  int row = blockIdx.x * 4 + (threadIdx.x >> 6);
  int lane = threadIdx.x & 63;
  size_t base = (size_t)row * 512 + lane * 8;
  if (row >= M){
    u16x8 z8 = {0, 0, 0, 0, 0, 0, 0, 0};
    *reinterpret_cast<u16x8*>(outb + base) = z8;
    return;
  }
  f32x4 v0 = *reinterpret_cast<const f32x4*>(xin + base);
  f32x4 v1 = *reinterpret_cast<const f32x4*>(xin + base + 4);
  float sall = v0[0] + v0[1] + v0[2] + v0[3] + v1[0] + v1[1] + v1[2] + v1[3];
  #pragma unroll
  for (int o = 32; o; o >>= 1) sall += __shfl_xor(sall, o, 64);
  float mean = sall * (1.f / 512.f);
  float d[8];
  #pragma unroll
  for (int e = 0; e < 4; e++){ d[e] = v0[e] - mean; d[4 + e] = v1[e] - mean; }
  float sq = 0.f;
  #pragma unroll
  for (int e = 0; e < 8; e++) sq += d[e] * d[e];
  #pragma unroll
  for (int o = 32; o; o >>= 1) sq += __shfl_xor(sq, o, 64);
  float rstd = 1.f / sqrtf(sq * (1.f / 512.f) + 1e-5f);
  f32x4 s0 = *reinterpret_cast<const f32x4*>(sg + lane * 8);
  f32x4 s1 = *reinterpret_cast<const f32x4*>(sg + lane * 8 + 4);
  f32x4 g0 = *reinterpret_cast<const f32x4*>(bg + lane * 8);
  f32x4 g1 = *reinterpret_cast<const f32x4*>(bg + lane * 8 + 4);
  u16x8 yb;
  #pragma unroll
  for (int e = 0; e < 4; e++){
    yb[e]     = f2bf(d[e] * rstd * s0[e] + g0[e]);
    yb[4 + e] = f2bf(d[4 + e] * rstd * s1[e] + g1[e]);
  }
  *reinterpret_cast<u16x8*>(outb + base) = yb;
}

// ---------------- fused residual-add + LayerNorm (bf16 in) ----------------
// MODE 0: write seqb (bf16). MODE 1 (final): write mapped rows of `out` (fp32).
template<int MODE>
__global__ __launch_bounds__(256) void lnres4_kernel(const unsigned short* __restrict__ cin,
    unsigned short* __restrict__ seqb, float* __restrict__ out,
    const float* __restrict__ sg, const float* __restrict__ bg, int M)
{
  int row = blockIdx.x * 4 + (threadIdx.x >> 6);
  int lane = threadIdx.x & 63;
  size_t base = (size_t)row * 512 + lane * 8;
  if (row >= M){
    if (MODE == 0){
      u16x8 z8 = {0, 0, 0, 0, 0, 0, 0, 0};
      *reinterpret_cast<u16x8*>(seqb + base) = z8;
    }
    return;
  }
  u16x8 cv = *reinterpret_cast<const u16x8*>(cin + base);
  u16x8 rv = *reinterpret_cast<const u16x8*>(seqb + base);
  float v[8];
  #pragma unroll
  for (int e = 0; e < 8; e++) v[e] = bf2f(cv[e]) + bf2f(rv[e]);
  float sall = 0.f;
  #pragma unroll
  for (int e = 0; e < 8; e++) sall += v[e];
  #pragma unroll
  for (int o = 32; o; o >>= 1) sall += __shfl_xor(sall, o, 64);
  float mean = sall * (1.f / 512.f);
  float sq = 0.f;
  #pragma unroll
  for (int e = 0; e < 8; e++){ v[e] -= mean; sq += v[e] * v[e]; }
  #pragma unroll
  for (int o = 32; o; o >>= 1) sq += __shfl_xor(sq, o, 64);
  float rstd = 1.f / sqrtf(sq * (1.f / 512.f) + 1e-5f);
  f32x4 s0 = *reinterpret_cast<const f32x4*>(sg + lane * 8);
  f32x4 s1 = *reinterpret_cast<const f32x4*>(sg + lane * 8 + 4);
  f32x4 g0 = *reinterpret_cast<const f32x4*>(bg + lane * 8);
  f32x4 g1 = *reinterpret_cast<const f32x4*>(bg + lane * 8 + 4);
  f32x4 y0, y1;
  #pragma unroll
  for (int e = 0; e < 4; e++){
    y0[e] = v[e] * rstd * s0[e] + g0[e];
    y1[e] = v[4 + e] * rstd * s1[e] + g1[e];
  }
  if (MODE == 0){
    u16x8 yb;
    #pragma unroll
    for (int e = 0; e < 4; e++){ yb[e] = f2bf(y0[e]); yb[4 + e] = f2bf(y1[e]); }
    *reinterpret_cast<u16x8*>(seqb + base) = yb;
  } else {
    int b = row / NTOT_C, n = row - b * NTOT_C;
    int o;
    if      (n < 1000) o = n;
    else if (n < 1024) o = -1;
    else if (n < 1274) o = n - 24;
    else if (n < 1280) o = -1;
    else if (n < 1343) o = n - 30;
    else if (n == 1343) o = -1;
    else               o = n - 31;
    if (o >= 0){
      size_t ob = ((size_t)b * 1334 + o) * 512 + lane * 8;
      *reinterpret_cast<f32x4*>(out + ob) = y0;
      *reinterpret_cast<f32x4*>(out + ob + 4) = y1;
    }
  }
}

// ---------------- ALL weight transposes fp32(K,N) -> bf16(N,K), one dispatch ----------------
__global__ __launch_bounds__(256) void wconv_all(
    const float* __restrict__ wq, const float* __restrict__ wk,
    const float* __restrict__ wv, const float* __restrict__ wo,
    const float* __restrict__ w1, const float* __restrict__ w2,
    unsigned short* __restrict__ qkvT, unsigned short* __restrict__ woT,
    unsigned short* __restrict__ w1T, unsigned short* __restrict__ w2T)
{
  __shared__ float tile[32][33];
  int bid = blockIdx.x;
  const float* wl; unsigned short* wtl; int N, K, n0, k0;
  if (bid < 4096){
    int part = bid >> 10, t = bid & 1023;
    int l = t >> 8, t2 = t & 255;
    k0 = (t2 >> 4) * 32; n0 = (t2 & 15) * 32;
    N = 512; K = 512;
    const float* s = (part == 0) ? wq : (part == 1) ? wk : (part == 2) ? wv : wo;
    wl = s + (size_t)l * 512 * 512;
    wtl = (part < 3) ? (qkvT + (size_t)l * 1536 * 512 + (size_t)part * 512 * 512)
                     : (woT + (size_t)l * 512 * 512);
  } else if (bid < 8192){
    int t = bid - 4096, l = t >> 10, t2 = t & 1023;
    k0 = (t2 >> 6) * 32; n0 = (t2 & 63) * 32;
    N = 2048; K = 512;
    wl = w1 + (size_t)l * 512 * 2048;
    wtl = w1T + (size_t)l * 2048 * 512;
  } else {
    int t = bid - 8192, l = t >> 10, t2 = t & 1023;
    k0 = (t2 >> 4) * 32; n0 = (t2 & 15) * 32;
    N = 512; K = 2048;
    wl = w2 + (size_t)l * 2048 * 512;
    wtl = w2T + (size_t)l * 512 * 2048;
  }
  int c = threadIdx.x & 31, r8 = threadIdx.x >> 5;
  #pragma unroll
  for (int p = 0; p < 4; p++){ int r = r8 + p * 8; tile[r][c] = wl[(size_t)(k0 + r) * N + n0 + c]; }
  __syncthreads();
  #pragma unroll
  for (int p = 0; p < 4; p++){ int r = r8 + p * 8; wtl[(size_t)(n0 + r) * K + k0 + c] = f2bf(tile[c][r]); }
}

// ================= 4-wave bf16 MFMA GEMM, BK=64, XCD-co-located (r15 champion) =================
// 1-D grid; groups of 8 M-stripes -> one stripe per XCD L2 (A fetched once).
// K-loop: 2-deep counted-vmcnt pipeline, both-sides XOR swizzle, setprio.
// Direct-store epilogue (measured best; LDS round-trip regressed in r14).
// EPI: 1 = bf16, 2 = bias+gelu -> bf16, 4 = bias -> bf16
template<int EPI, int BM, int BN>
__global__ __launch_bounds__(256) void gemm2_kernel(
    const unsigned short* __restrict__ A, const unsigned short* __restrict__ Wt,
    unsigned short* __restrict__ Cb, const float* __restrict__ bias,
    int N, int K, int GX, int GY)
{
  constexpr int MF = BM / 32, NF = BN / 32;
  constexpr int LA = BM / 32, LB = BN / 32;
  __shared__ __align__(16) unsigned short Abuf[2][BM * 64];
  __shared__ __align__(16) unsigned short Bbuf[2][BN * 64];
  const int tid = threadIdx.x;
  const int wid = tid >> 6, lane = tid & 63;
  const int wm2 = wid >> 1, wn2 = wid & 1;
  const int r16 = lane & 15, g = lane >> 4;

  // ---- XCD co-location swizzle (groups of 8 M-stripes) ----
  int wg = blockIdx.x;
  int group = wg / (8 * GX);
  int rem   = wg - group * 8 * GX;
  int gbase = group * 8;
  int m_t, n_t;
  if (gbase + 8 <= GY){ m_t = gbase + (rem & 7); n_t = rem >> 3; }
  else { int r = GY - gbase; m_t = gbase + rem % r; n_t = rem / r; }
  const int m0 = m_t * BM, n0 = n_t * BN;

  const int row0 = tid >> 3;
  const int scol = ((tid & 7) ^ (row0 & 7)) * 8;
  const unsigned short* gAs = A  + (size_t)(m0 + row0) * K + scol;
  const unsigned short* gBs = Wt + (size_t)(n0 + row0) * K + scol;

  const int swz0 = ((0 + g) ^ (r16 & 7)) * 8;
  const int swz1 = ((4 + g) ^ (r16 & 7)) * 8;
  const int arow = (wm2 * (BM / 2) + r16) * 64;
  const int brow = (wn2 * (BN / 2) + r16) * 64;

  const int nt = K >> 6;
  f32x4 acc[MF][NF] = {};

  auto STAGE_A = [&](int buf, int kt){
    #pragma unroll
    for (int q = 0; q < LA; q++)
      GLD_LDS16(gAs + kt * 64 + (size_t)q * 32 * K, &Abuf[buf][q * 2048 + tid * 8]);
  };
  auto STAGE_B = [&](int buf, int kt){
    #pragma unroll
    for (int q = 0; q < LB; q++)
      GLD_LDS16(gBs + kt * 64 + (size_t)q * 32 * K, &Bbuf[buf][q * 2048 + tid * 8]);
  };

  cfence();
  STAGE_A(0, 0); STAGE_B(0, 0);
  if (nt > 1){ STAGE_A(1, 1); waitcnt_vm<LA>(); }
  else        { waitcnt_vm<0>(); }
  __builtin_amdgcn_s_barrier();
  cfence();

  for (int t = 0; t < nt; t++){
    const int d = t & 1;
    const unsigned short* Ab = Abuf[d];
    const unsigned short* Bb = Bbuf[d];

    bf16x8 a0[MF], b0[NF];
    #pragma unroll
    for (int m = 0; m < MF; m++) a0[m] = *reinterpret_cast<const bf16x8*>(&Ab[arow + m * 1024 + swz0]);
    #pragma unroll
    for (int n = 0; n < NF; n++) b0[n] = *reinterpret_cast<const bf16x8*>(&Bb[brow + n * 1024 + swz0]);
    if (t + 1 < nt){ cfence(); STAGE_B(d ^ 1, t + 1); cfence(); }
    __builtin_amdgcn_s_setprio(1);
    #pragma unroll
    for (int m = 0; m < MF; m++)
      #pragma unroll
      for (int n = 0; n < NF; n++)
        acc[m][n] = __builtin_amdgcn_mfma_f32_16x16x32_bf16(a0[m], b0[n], acc[m][n], 0, 0, 0);
    __builtin_amdgcn_s_setprio(0);

    bf16x8 a1[MF], b1v[NF];
    #pragma unroll
    for (int m = 0; m < MF; m++) a1[m] = *reinterpret_cast<const bf16x8*>(&Ab[arow + m * 1024 + swz1]);
    #pragma unroll
    for (int n = 0; n < NF; n++) b1v[n] = *reinterpret_cast<const bf16x8*>(&Bb[brow + n * 1024 + swz1]);
    waitcnt_lgkm0();
    __builtin_amdgcn_s_barrier();
    cfence();
    if (t + 2 < nt){ STAGE_A(d, t + 2); cfence(); }
    __builtin_amdgcn_s_setprio(1);
    #pragma unroll
    for (int m = 0; m < MF; m++)
      #pragma unroll
      for (int n = 0; n < NF; n++)
        acc[m][n] = __builtin_amdgcn_mfma_f32_16x16x32_bf16(a1[m], b1v[n], acc[m][n], 0, 0, 0);
    __builtin_amdgcn_s_setprio(0);

    if (t + 1 < nt){
      if (t + 2 < nt) waitcnt_vm<LA>();
      else            waitcnt_vm<0>();
      __builtin_amdgcn_s_barrier();
      cfence();
    }
  }

  const int colBase = n0 + wn2 * (BN / 2) + r16;
  #pragma unroll
  for (int m = 0; m < MF; m++){
    int row = m0 + wm2 * (BM / 2) + m * 16 + g * 4;
    #pragma unroll
    for (int n = 0; n < NF; n++){
      int col = colBase + n * 16;
      float bsv = (EPI >= 2) ? bias[col] : 0.f;
      #pragma unroll
      for (int j = 0; j < 4; j++){
        float v = acc[m][n][j];
        if (EPI >= 2) v += bsv;
        if (EPI == 2) v = gelu_f(v);
        Cb[(size_t)(row + j) * N + col] = f2bf(v);
      }
    }
  }
}

// ---------------- sparse tree attention: one wave per (b,n), all 8 heads ----------------
__global__ __launch_bounds__(256) void attn_kernel(
    const unsigned short* __restrict__ qkv, unsigned short* __restrict__ ctx)
{
  int wid = blockIdx.x * 4 + (threadIdx.x >> 6);
  int lane = threadIdx.x & 63;
  int n = wid % NTOT_C;
  int b = wid / NTOT_C;

  int i, sz, of, cb, par;
  if (n < 1024){ i = n;        sz = 1024; of = 0;    cb = -1;            par = 1024 + (i >> 2); }
  else if (n < 1280){ i = n - 1024; sz = 256; of = 1024; cb = 0    + 4 * i; par = 1280 + (i >> 2); }
  else if (n < 1344){ i = n - 1280; sz = 64;  of = 1280; cb = 1024 + 4 * i; par = 1344 + (i >> 2); }
  else if (n < 1360){ i = n - 1344; sz = 16;  of = 1344; cb = 1280 + 4 * i; par = 1360 + (i >> 2); }
  else if (n < 1364){ i = n - 1360; sz = 4;   of = 1360; cb = 1344 + 4 * i; par = 1364; }
  else { i = 0; sz = 1; of = 1364; cb = 1360; par = -1; }

  int nb[10];
  #pragma unroll
  for (int s5 = 0; s5 < 5; s5++){ int pos = i - 2 + s5; nb[s5] = (pos >= 0 && pos < sz) ? of + pos : -1; }
  #pragma unroll
  for (int r = 0; r < 4; r++) nb[5 + r] = (cb >= 0) ? cb + r : -1;
  nb[9] = par;

  const unsigned short* rows = qkv + ((size_t)b * NTOT_C) * 1536;

  u16x8 qv = *reinterpret_cast<const u16x8*>(rows + (size_t)n * 1536 + lane * 8);
  float qf[8];
  #pragma unroll
  for (int e = 0; e < 8; e++) qf[e] = bf2f(qv[e]);

  float sc[10];
  #pragma unroll
  for (int j = 0; j < 10; j++){
    int id = nb[j] >= 0 ? nb[j] : n;
    u16x8 kv = *reinterpret_cast<const u16x8*>(rows + (size_t)id * 1536 + 512 + lane * 8);
    float p = 0.f;
    #pragma unroll
    for (int e = 0; e < 8; e++) p += qf[e] * bf2f(kv[e]);
    p += __shfl_xor(p, 1, 64);
    p += __shfl_xor(p, 2, 64);
    p += __shfl_xor(p, 4, 64);
    sc[j] = (nb[j] >= 0) ? p * 0.125f : -1e30f;
  }
  float mx = sc[0];
  #pragma unroll
  for (int j = 1; j < 10; j++) mx = fmaxf(mx, sc[j]);
  float den = 0.f;
  float wj[10];
  #pragma unroll
  for (int j = 0; j < 10; j++){
    wj[j] = (nb[j] >= 0) ? expf(sc[j] - mx) : 0.f;
    den += wj[j];
  }
  float rden = 1.f / den;
  float accv[8] = {};
  #pragma unroll
  for (int j = 0; j < 10; j++){
    int id = nb[j] >= 0 ? nb[j] : n;
    u16x8 vv = *reinterpret_cast<const u16x8*>(rows + (size_t)id * 1536 + 1024 + lane * 8);
    float w = wj[j];
    #pragma unroll
    for (int e = 0; e < 8; e++) accv[e] += w * bf2f(vv[e]);
  }
  u16x8 ov;
  #pragma unroll
  for (int e = 0; e < 8; e++) ov[e] = f2bf(accv[e] * rden);
  *reinterpret_cast<u16x8*>(ctx + ((size_t)b * NTOT_C + n) * 512 + lane * 8) = ov;
}

extern "C" void kernel_launch(void* const* d_in, const int* in_sizes, int n_in,
                              void* d_out, int out_size, void* d_ws, size_t ws_size,
                              hipStream_t stream)
{
  const float* x      = (const float*)d_in[0];
  const float* conv_w = (const float*)d_in[1];
  const float* norm_s = (const float*)d_in[2];
  const float* norm_b = (const float*)d_in[3];
  const float* wq     = (const float*)d_in[4];
  const float* wk     = (const float*)d_in[5];
  const float* wv     = (const float*)d_in[6];
  const float* wo     = (const float*)d_in[7];
  const float* ln1_s  = (const float*)d_in[8];
  const float* ln1_b  = (const float*)d_in[9];
  const float* w1     = (const float*)d_in[10];
  const float* b1     = (const float*)d_in[11];
  const float* w2     = (const float*)d_in[12];
  const float* b2     = (const float*)d_in[13];
  const float* ln2_s  = (const float*)d_in[14];
  const float* ln2_b  = (const float*)d_in[15];
  float* out = (float*)d_out;

  char* ws = (char*)d_ws;
  size_t off = 0;
  auto alloc = [&](size_t bytes) -> char* {
    char* p = ws + off; off += (bytes + 255) & ~(size_t)255; return p;
  };
  unsigned short* qkvT = (unsigned short*)alloc((size_t)NLAY * 1536 * 512 * 2);
  unsigned short* woT  = (unsigned short*)alloc((size_t)NLAY * 512 * 512 * 2);
  unsigned short* w1T  = (unsigned short*)alloc((size_t)NLAY * 2048 * 512 * 2);
  unsigned short* w2T  = (unsigned short*)alloc((size_t)NLAY * 512 * 2048 * 2);
  float*          seqf = (float*)alloc((size_t)M_PAD * 512 * 4);
  unsigned short* seqb = (unsigned short*)alloc((size_t)M_PAD * 512 * 2);
  float*          buff = (float*)alloc((size_t)M_PAD * 512 * 4);   // pe (pre-loop) + delta (in-loop)
  unsigned short* qkvb = (unsigned short*)alloc((size_t)M_PAD * 1536 * 2);
  unsigned short* ctxb = (unsigned short*)alloc((size_t)M_PAD * 512 * 2);
  unsigned short* ffn1 = qkvb;                 // alias: M_PAD x 2048 fits in qkvb+ctxb region
  float*          pe   = buff;                 // alias, pre-loop only
  unsigned short* delta = (unsigned short*)buff;  // alias, in-loop bf16 GEMM output

  // all weight transposes in one dispatch
  wconv_all<<<12288, 256, 0, stream>>>(wq, wk, wv, wo, w1, w2, qkvT, woT, w1T, w2T);

  pe_kernel<<<(SEQN * 512) / 256, 256, 0, stream>>>(pe);
  conv_kernel<<<dim3(4,16,BQ), 256, 0, stream>>>(x, conv_w, pe, seqf);
  const int psz[6]  = {1024, 256, 64, 16, 4, 1};
  const int poff[6] = {0, 1024, 1280, 1344, 1360, 1364};
  for (int l = 0; l < 5; l++)
    pool_kernel<<<(BQ * psz[l+1] * 512) / 256, 256, 0, stream>>>(seqf, poff[l], poff[l+1], psz[l+1]);
  ln4_kernel<<<M_PAD / 4, 256, 0, stream>>>(seqf, seqb, norm_s, norm_b, M_REAL);

  for (int l = 0; l < NLAY; l++){
    // QKV: 128x128, GX=12 x GY=86, XCD-co-located
    gemm2_kernel<1,128,128><<<12*86,256,0,stream>>>(seqb, qkvT + (size_t)l*1536*512, qkvb, nullptr, 1536, 512, 12, 86);
    attn_kernel<<<(BQ * NTOT_C + 3) / 4, 256, 0, stream>>>(qkvb, ctxb);
    // WO: 64x128, GX=4 x GY=172 -> bf16 delta
    gemm2_kernel<1,64,128><<<4*172,256,0,stream>>>(ctxb, woT + (size_t)l*512*512, delta, nullptr, 512, 512, 4, 172);
    lnres4_kernel<0><<<M_PAD / 4,256,0,stream>>>(delta, seqb, nullptr, ln1_s + l*512, ln1_b + l*512, M_REAL);
    // FFN1: 128x128, GX=16 x GY=86; bias+gelu -> bf16
    gemm2_kernel<2,128,128><<<16*86,256,0,stream>>>(seqb, w1T + (size_t)l*2048*512, ffn1, b1 + l*2048, 2048, 512, 16, 86);
    // FFN2: 64x128, GX=4 x GY=172, K=2048; bias -> bf16 delta
    gemm2_kernel<4,64,128><<<4*172,256,0,stream>>>(ffn1, w2T + (size_t)l*512*2048, delta, b2 + l*512, 512, 2048, 4, 172);
    if (l < NLAY - 1)
      lnres4_kernel<0><<<M_PAD / 4,256,0,stream>>>(delta, seqb, nullptr, ln2_s + l*512, ln2_b + l*512, M_REAL);
    else
      lnres4_kernel<1><<<M_PAD / 4,256,0,stream>>>(delta, seqb, out, ln2_s + l*512, ln2_b + l*512, M_REAL);
  }
}